// Round 4
// baseline (6557.813 us; speedup 1.0000x reference)
//
#include <hip/hip_runtime.h>

typedef unsigned short u16;
typedef unsigned long long u64;
typedef short v8s __attribute__((ext_vector_type(8)));
typedef float v4f __attribute__((ext_vector_type(4)));

#define Bb 256
#define Tt 512
#define Dd 64
#define Hh 512
#define G4 2048

#define NGROUP 4
#define NCHUNK 32
#define BT 64
#define HC 16
#define NCOL 64

#define WHH_S 520   // 512 + 8 pad (bf16 elems)
#define WIH_S 72    // 64 + 8 pad
#define GAT_S 68    // 64 + 4 pad (fp32 elems)
#define SMEM_BYTES (NCOL*WHH_S*2 + NCOL*WIH_S*2 + NCOL*GAT_S*4)  // 93184

#define MFMA(a,b,c) __builtin_amdgcn_mfma_f32_16x16x32_bf16((a),(b),(c),0,0,0)

__device__ __forceinline__ u16 f2bf(float f) {
  unsigned u = __float_as_uint(f);
  unsigned r = (u + 0x7fffu + ((u >> 16) & 1u)) >> 16;
  return (u16)r;
}
__device__ __forceinline__ float bf2f(u16 v) {
  return __uint_as_float(((unsigned)v) << 16);
}
__device__ __forceinline__ float sigm(float x) { return 1.0f / (1.0f + __expf(-x)); }
__device__ __forceinline__ float tanh_f(float x) {
  float a = fabsf(x);
  float e = __expf(-2.0f * a);
  float r = (1.0f - e) / (1.0f + e);
  return copysignf(r, x);
}
__device__ __forceinline__ float softplus_f(float x) { return log1pf(__expf(x)); }

// ---------------------------------------------------------------- prep:
// x fp32 [B][T][D] -> bf16 [T][B][D]; zero sync flags.
__global__ void k_prep(const float* __restrict__ x, u16* __restrict__ x_bf,
                       unsigned* __restrict__ flags)
{
  if (blockIdx.x == 0 && threadIdx.x < NGROUP * NCHUNK) flags[threadIdx.x] = 0u;
  const int N4 = Tt * Bb * Dd / 4;
  int stride = gridDim.x * blockDim.x;
  for (int i = blockIdx.x * blockDim.x + threadIdx.x; i < N4; i += stride) {
    int idx = i * 4;
    int t = idx >> 14;          // / (B*D)
    int rem = idx & 16383;
    int b = rem >> 6;
    int d = rem & 63;
    float4 v = *(const float4*)(x + (size_t)b * (Tt * Dd) + t * Dd + d);
    unsigned lo = (unsigned)f2bf(v.x) | ((unsigned)f2bf(v.y) << 16);
    unsigned hi = (unsigned)f2bf(v.z) | ((unsigned)f2bf(v.w) << 16);
    *(uint2*)(x_bf + idx) = make_uint2(lo, hi);
  }
}

// ---------------------------------------------------------------- main:
// persistent LSTM. grid = 128 blocks (4 batch groups x 32 hidden chunks),
// 256 threads. w_hh/w_ih chunk sampled into LDS once; 512 steps with
// flag-based producer/consumer sync per batch group.
// h exchange: producers STORE write-through to L3 (sc0 sc1 -> L2 never
// dirty, no wbl2 needed); consumers observe the flag (sc poll), issue ONE
// acquire fence (buffer_inv: L2 invalidate), then READ h via the normal
// CACHED path -> one L3 refill per 64B line per XCD, everyone else hits
// L2. This cuts the uncached-fabric traffic ~8x vs all-sc reads (which
// were concurrency-limited to ~2.3 TB/s).
__global__ __launch_bounds__(256, 1) void lstm_main(
    const float* __restrict__ whh_mu, const float* __restrict__ whh_rho, const float* __restrict__ whh_eps,
    const float* __restrict__ wih_mu, const float* __restrict__ wih_rho, const float* __restrict__ wih_eps,
    const float* __restrict__ b_mu,  const float* __restrict__ b_rho,  const float* __restrict__ b_eps,
    const u16* __restrict__ x_bf, u16* __restrict__ h_buf, unsigned* __restrict__ flags)
{
  extern __shared__ char smem[];
  u16*   w_hh_lds = (u16*)smem;                       // [NCOL][WHH_S]
  u16*   w_ih_lds = w_hh_lds + NCOL * WHH_S;          // [NCOL][WIH_S]
  float* gates    = (float*)(w_ih_lds + NCOL * WIH_S);// [NCOL][GAT_S]

  const int tid   = threadIdx.x;
  const int g     = blockIdx.x & 3;    // batch group
  const int chunk = blockIdx.x >> 2;   // hidden chunk
  const int b0    = g * BT;
  const int j0    = chunk * HC;

  // ---- sample weight chunk into LDS (bf16). local col lc = gate*16 + jj
  {
    const int lc = tid & 63;
    const int gcol = (lc >> 4) * Hh + j0 + (lc & 15);  // global gate column
    for (int k = tid >> 6; k < Hh; k += 4) {
      int gi = k * G4 + gcol;
      float w = whh_mu[gi] + softplus_f(whh_rho[gi]) * whh_eps[gi];
      w_hh_lds[lc * WHH_S + k] = f2bf(w);
    }
    for (int k = tid >> 6; k < Dd; k += 4) {
      int gi = k * G4 + gcol;
      float w = wih_mu[gi] + softplus_f(wih_rho[gi]) * wih_eps[gi];
      w_ih_lds[lc * WIH_S + k] = f2bf(w);
    }
  }

  // ---- c/h-update mapping: thread owns batch ub x 4 units (jg*4..jg*4+3)
  const int ub = tid >> 2;     // batch within group, 0..63
  const int jg = tid & 3;      // unit quad, 0..3
  float bias[4][4];            // [gate][u]
  #pragma unroll
  for (int gt = 0; gt < 4; ++gt)
    #pragma unroll
    for (int u = 0; u < 4; ++u) {
      int colg = gt * Hh + j0 + jg * 4 + u;
      bias[gt][u] = b_mu[colg] + softplus_f(b_rho[colg]) * b_eps[colg];
    }
  __syncthreads();

  // ---- MFMA geometry: 4 waves tile the 64x64 gate tile as 2x2 of 32x32
  const int lane = tid & 63;
  const int wv   = tid >> 6;
  const int wm0  = (wv & 1) * 32;
  const int wn0  = (wv >> 1) * 32;
  const int lm   = lane & 15;
  const int ko   = (lane >> 4) * 8;

  const u16* Bh0 = w_hh_lds + (wn0 + lm) * WHH_S + ko;
  const u16* Bh1 = Bh0 + 16 * WHH_S;
  const u16* Bx0 = w_ih_lds + (wn0 + lm) * WIH_S + ko;
  const u16* Bx1 = Bx0 + 16 * WIH_S;

  const int arow = b0 + wm0 + lm;   // A-fragment row in global h / x

  float cc[4] = {0.f, 0.f, 0.f, 0.f};   // persistent cell state
  const int fbase = g * NCHUNK;

  for (int t = 0; t < Tt; ++t) {
    v4f a00 = {0.f, 0.f, 0.f, 0.f};
    v4f a01 = {0.f, 0.f, 0.f, 0.f};
    v4f a10 = {0.f, 0.f, 0.f, 0.f};
    v4f a11 = {0.f, 0.f, 0.f, 0.f};

    // ---- input projection first: h-independent, overlaps the flag wait
    {
      const u16* xa = x_bf + (size_t)t * (Bb * Dd) + arow * Dd + ko;
      #pragma unroll
      for (int ks = 0; ks < 2; ++ks) {
        v8s a0 = *(const v8s*)(xa + ks * 32);
        v8s a1 = *(const v8s*)(xa + 16 * Dd + ks * 32);
        v8s w0 = *(const v8s*)(Bx0 + ks * 32);
        v8s w1 = *(const v8s*)(Bx1 + ks * 32);
        a00 = MFMA(a0, w0, a00);
        a01 = MFMA(a0, w1, a01);
        a10 = MFMA(a1, w0, a10);
        a11 = MFMA(a1, w1, a11);
      }
    }

    // ---- wait until all chunks of this group published h_t (L3 polls)
    if (t > 0) {
      if (tid < NCHUNK) {
        while (__hip_atomic_load(&flags[fbase + tid], __ATOMIC_RELAXED,
                                 __HIP_MEMORY_SCOPE_SYSTEM) < (unsigned)t) { }
      }
      __syncthreads();
      // acquire: invalidates L1 + this XCD's L2 so the cached h-loads
      // below see the producers' L3 write-through data. L2 is never
      // dirty (all cross-block stores are sc0 sc1), so no writeback.
      __builtin_amdgcn_fence(__ATOMIC_ACQUIRE, "agent");

      // ---- recurrent GEMM: K = 512, A via NORMAL cached loads (L2 hits
      // for all but the first toucher per XCD). Compiler pipelines these.
      const u16* hc  = h_buf + (t & 1) * (Bb * Hh);
      const u16* ha0 = hc + arow * Hh + ko;
      const u16* ha1 = ha0 + 16 * Hh;
      #pragma unroll
      for (int ks = 0; ks < 16; ++ks) {
        v8s a0 = *(const v8s*)(ha0 + ks * 32);
        v8s a1 = *(const v8s*)(ha1 + ks * 32);
        v8s w0 = *(const v8s*)(Bh0 + ks * 32);
        v8s w1 = *(const v8s*)(Bh1 + ks * 32);
        a00 = MFMA(a0, w0, a00);
        a01 = MFMA(a0, w1, a01);
        a10 = MFMA(a1, w0, a10);
        a11 = MFMA(a1, w1, a11);
      }
    }

    // ---- stage gates to LDS: layout [col][row], C-frag row=(lane>>4)*4+reg
    {
      const int colb = wn0 + lm;
      const int rowb = wm0 + ((lane >> 4) << 2);
      *(v4f*)&gates[(colb     ) * GAT_S + rowb     ] = a00;
      *(v4f*)&gates[(colb + 16) * GAT_S + rowb     ] = a01;
      *(v4f*)&gates[(colb     ) * GAT_S + rowb + 16] = a10;
      *(v4f*)&gates[(colb + 16) * GAT_S + rowb + 16] = a11;
    }
    __syncthreads();

    // ---- c/h update: thread owns batch ub x units jg*4..jg*4+3
    {
      u16* hn = h_buf + ((t + 1) & 1) * (Bb * Hh);
      unsigned hv2[2];
      u16* hv = (u16*)hv2;
      #pragma unroll
      for (int u = 0; u < 4; ++u) {
        int j = jg * 4 + u;
        float iv = gates[(      j) * GAT_S + ub];
        float fv = gates[(16 + j) * GAT_S + ub];
        float gv = gates[(32 + j) * GAT_S + ub];
        float ov = gates[(48 + j) * GAT_S + ub];
        float ig = sigm(iv + bias[0][u]);
        float fg = sigm(fv + bias[1][u]);
        float gg = tanh_f(gv + bias[2][u]);
        float og = sigm(ov + bias[3][u]);
        cc[u] = fg * cc[u] + ig * gg;
        hv[u] = f2bf(og * tanh_f(cc[u]));
      }
      // one contiguous 8B write-through (sc0 sc1) store: 4 bf16 -> L3.
      u64 q = (u64)hv2[0] | ((u64)hv2[1] << 32);
      __hip_atomic_store((u64*)&hn[(b0 + ub) * Hh + j0 + jg * 4], q,
                         __ATOMIC_RELAXED, __HIP_MEMORY_SCOPE_SYSTEM);
    }

    // ---- publish: wait store-ack (per-wave), join waves, set flag (L3)
    asm volatile("s_waitcnt vmcnt(0)" ::: "memory");
    __syncthreads();
    if (tid == 0) {
      __hip_atomic_store(&flags[fbase + chunk], (unsigned)(t + 1),
                         __ATOMIC_RELAXED, __HIP_MEMORY_SCOPE_SYSTEM);
    }
  }
}

// ---------------------------------------------------------------- epilogue:
// out[b] = h_last[b,:] . lin_w + lin_b   (h_last in h_buf[0], since T even)
__global__ void k_out(const u16* __restrict__ h, const float* __restrict__ lw,
                      const float* __restrict__ lb, float* __restrict__ out)
{
  int b = blockIdx.x * 64 + threadIdx.x;
  if (b >= Bb) return;
  const u16* hr = h + b * Hh;
  float acc = 0.f;
  #pragma unroll 8
  for (int k = 0; k < Hh; ++k) acc += bf2f(hr[k]) * lw[k];
  out[b] = acc + lb[0];
}

extern "C" void kernel_launch(void* const* d_in, const int* in_sizes, int n_in,
                              void* d_out, int out_size, void* d_ws, size_t ws_size,
                              hipStream_t stream)
{
  (void)in_sizes; (void)n_in; (void)out_size; (void)ws_size;
  const float* x       = (const float*)d_in[0];
  const float* wih_mu  = (const float*)d_in[1];
  const float* wih_rho = (const float*)d_in[2];
  const float* wih_eps = (const float*)d_in[3];
  const float* whh_mu  = (const float*)d_in[4];
  const float* whh_rho = (const float*)d_in[5];
  const float* whh_eps = (const float*)d_in[6];
  const float* b_mu    = (const float*)d_in[7];
  const float* b_rho   = (const float*)d_in[8];
  const float* b_eps   = (const float*)d_in[9];
  const float* lin_w   = (const float*)d_in[10];
  const float* lin_b   = (const float*)d_in[11];
  float* out = (float*)d_out;

  // workspace layout
  u16* x_bf  = (u16*)d_ws;                       // T*B*D bf16  = 16 MB
  u16* h_buf = x_bf + (size_t)Tt * Bb * Dd;      // 2*B*H bf16  = 512 KB
  unsigned* flags = (unsigned*)(h_buf + 2 * Bb * Hh);  // 128 uints

  k_prep<<<2048, 256, 0, stream>>>(x, x_bf, flags);

  hipFuncSetAttribute(reinterpret_cast<const void*>(lstm_main),
                      hipFuncAttributeMaxDynamicSharedMemorySize, SMEM_BYTES);
  lstm_main<<<NGROUP * NCHUNK, 256, SMEM_BYTES, stream>>>(
      whh_mu, whh_rho, whh_eps, wih_mu, wih_rho, wih_eps,
      b_mu, b_rho, b_eps, x_bf, h_buf, flags);

  k_out<<<(Bb + 63) / 64, 64, 0, stream>>>(h_buf, lin_w, lin_b, out);
}

// Round 5
// 2717.805 us; speedup vs baseline: 2.4129x; 2.4129x over previous
//
#include <hip/hip_runtime.h>

typedef unsigned short u16;
typedef unsigned long long u64;
typedef short v8s __attribute__((ext_vector_type(8)));
typedef float v4f __attribute__((ext_vector_type(4)));
typedef unsigned v2u __attribute__((ext_vector_type(2)));

#define Bb 256
#define Tt 512
#define Dd 64
#define Hh 512
#define G4 2048

#define NGROUP 8     // batch groups (32 batch each)
#define NCHUNK 32    // hidden chunks (16 hidden units -> 64 gate cols)
#define BT 32
#define HC 16
#define NCOL 64

#define WHH_S 520   // 512 + 8 pad (bf16 elems)
#define WIH_S 72    // 64 + 8 pad
#define SMEM_BYTES (NCOL*WHH_S*2 + NCOL*WIH_S*2)   // 75776

#define MFMA(a,b,c) __builtin_amdgcn_mfma_f32_16x16x32_bf16((a),(b),(c),0,0,0)

__device__ __forceinline__ u16 f2bf(float f) {
  unsigned u = __float_as_uint(f);
  unsigned r = (u + 0x7fffu + ((u >> 16) & 1u)) >> 16;
  return (u16)r;
}
__device__ __forceinline__ float bf2f(u16 v) {
  return __uint_as_float(((unsigned)v) << 16);
}
__device__ __forceinline__ float sigm(float x) { return 1.0f / (1.0f + __expf(-x)); }
__device__ __forceinline__ float tanh_f(float x) {
  float a = fabsf(x);
  float e = __expf(-2.0f * a);
  float r = (1.0f - e) / (1.0f + e);
  return copysignf(r, x);
}
__device__ __forceinline__ float softplus_f(float x) { return log1pf(__expf(x)); }

// ---------------------------------------------------------------- prep:
// x fp32 [B][T][D] -> bf16 [T][B][D]; zero sync flags.
__global__ void k_prep(const float* __restrict__ x, u16* __restrict__ x_bf,
                       unsigned* __restrict__ flags)
{
  if (blockIdx.x == 0 && threadIdx.x < NGROUP * NCHUNK) flags[threadIdx.x] = 0u;
  const int N4 = Tt * Bb * Dd / 4;
  int stride = gridDim.x * blockDim.x;
  for (int i = blockIdx.x * blockDim.x + threadIdx.x; i < N4; i += stride) {
    int idx = i * 4;
    int t = idx >> 14;          // / (B*D)
    int rem = idx & 16383;
    int b = rem >> 6;
    int d = rem & 63;
    float4 v = *(const float4*)(x + (size_t)b * (Tt * Dd) + t * Dd + d);
    unsigned lo = (unsigned)f2bf(v.x) | ((unsigned)f2bf(v.y) << 16);
    unsigned hi = (unsigned)f2bf(v.z) | ((unsigned)f2bf(v.w) << 16);
    *(uint2*)(x_bf + idx) = make_uint2(lo, hi);
  }
}

// ---------------------------------------------------------------- main:
// persistent LSTM. grid = 256 blocks (8 batch groups x 32 hidden chunks),
// 128 threads (2 waves). TRANSPOSED MFMA: A = sampled weights (LDS),
// B = h rows (global, sc0 sc1 direct-L3). C then has col=batch,
// row=gate-col, so each lane holds all 4 gates x 4 hidden x 1 batch ->
// LSTM update entirely in-register, h-write = one 8B contiguous store.
// Waves own disjoint 16-batch strips -> zero redundant h loads; 256 CUs
// all issue sc traffic (8 MB/step total, was 16 MB on 128 CUs).
__global__ __launch_bounds__(128, 1) void lstm_main(
    const float* __restrict__ whh_mu, const float* __restrict__ whh_rho, const float* __restrict__ whh_eps,
    const float* __restrict__ wih_mu, const float* __restrict__ wih_rho, const float* __restrict__ wih_eps,
    const float* __restrict__ b_mu,  const float* __restrict__ b_rho,  const float* __restrict__ b_eps,
    const u16* __restrict__ x_bf, u16* __restrict__ h_buf, unsigned* __restrict__ flags)
{
  extern __shared__ char smem[];
  u16* w_hh_lds = (u16*)smem;                 // [NCOL][WHH_S]
  u16* w_ih_lds = w_hh_lds + NCOL * WHH_S;    // [NCOL][WIH_S]

  const int tid   = threadIdx.x;
  const int g     = blockIdx.x & 7;    // batch group
  const int chunk = blockIdx.x >> 3;   // hidden chunk
  const int b0    = g * BT;
  const int j0    = chunk * HC;

  // ---- sample weight chunk into LDS (bf16). local col lc = gate*16 + jj
  {
    const int lc = tid & 63;
    const int gcol = (lc >> 4) * Hh + j0 + (lc & 15);  // global gate column
    for (int k = tid >> 6; k < Hh; k += 2) {
      int gi = k * G4 + gcol;
      float w = whh_mu[gi] + softplus_f(whh_rho[gi]) * whh_eps[gi];
      w_hh_lds[lc * WHH_S + k] = f2bf(w);
    }
    for (int k = tid >> 6; k < Dd; k += 2) {
      int gi = k * G4 + gcol;
      float w = wih_mu[gi] + softplus_f(wih_rho[gi]) * wih_eps[gi];
      w_ih_lds[lc * WIH_S + k] = f2bf(w);
    }
  }

  // ---- MFMA geometry
  const int lane = tid & 63;
  const int wv   = tid >> 6;          // wave: batch strip
  const int ln   = lane & 15;
  const int q    = lane >> 4;
  const int ko   = q * 8;

  // A-operand (weights) pointers, one per gate row-tile rt
  const u16* Wh[4]; const u16* Wx[4];
  #pragma unroll
  for (int rt = 0; rt < 4; ++rt) {
    Wh[rt] = w_hh_lds + (rt * 16 + ln) * WHH_S + ko;
    Wx[rt] = w_ih_lds + (rt * 16 + ln) * WIH_S + ko;
  }

  const int bat = b0 + wv * 16 + ln;   // this lane's batch row (B-operand)

  // ---- per-lane biases: gate rt, hidden j0 + q*4 + r
  float bs[4][4];
  #pragma unroll
  for (int rt = 0; rt < 4; ++rt)
    #pragma unroll
    for (int r = 0; r < 4; ++r) {
      int colg = rt * Hh + j0 + q * 4 + r;
      bs[rt][r] = b_mu[colg] + softplus_f(b_rho[colg]) * b_eps[colg];
    }

  float cc[4] = {0.f, 0.f, 0.f, 0.f};   // cell state: batch bat, hidden q*4+r
  const int fbase = g * NCHUNK;
  __syncthreads();

  for (int t = 0; t < Tt; ++t) {
    v4f ac0 = {0.f,0.f,0.f,0.f}, ac1 = {0.f,0.f,0.f,0.f};
    v4f ac2 = {0.f,0.f,0.f,0.f}, ac3 = {0.f,0.f,0.f,0.f};

    // ---- input projection first (h-independent, overlaps the flag wait)
    {
      const u16* xb = x_bf + (size_t)t * (Bb * Dd) + bat * Dd + ko;
      #pragma unroll
      for (int ks = 0; ks < 2; ++ks) {
        v8s xf = *(const v8s*)(xb + ks * 32);
        ac0 = MFMA(*(const v8s*)(Wx[0] + ks * 32), xf, ac0);
        ac1 = MFMA(*(const v8s*)(Wx[1] + ks * 32), xf, ac1);
        ac2 = MFMA(*(const v8s*)(Wx[2] + ks * 32), xf, ac2);
        ac3 = MFMA(*(const v8s*)(Wx[3] + ks * 32), xf, ac3);
      }
    }

    if (t > 0) {
      // ---- wait until all 32 chunks of this group published h_t
      if (tid < NCHUNK) {
        while (__hip_atomic_load(&flags[fbase + tid], __ATOMIC_RELAXED,
                                 __HIP_MEMORY_SCOPE_SYSTEM) < (unsigned)t) { }
      }
      __syncthreads();

      // ---- recurrent GEMM, K=512: 16 sc loads in flight, one drain
      const u16* hb = h_buf + (t & 1) * (Bb * Hh) + bat * Hh + ko;
      v8s Ahh[16];
      #pragma unroll
      for (int ks = 0; ks < 16; ++ks) {
        asm volatile("global_load_dwordx4 %0, %1, off offset:%c2 sc0 sc1"
                     : "=v"(Ahh[ks]) : "v"(hb), "i"(ks * 64));
      }
      asm volatile("s_waitcnt vmcnt(0)" ::: "memory");
      #pragma unroll
      for (int ks = 0; ks < 16; ++ks) {
        asm volatile("" : "+v"(Ahh[ks]));
      }
      #pragma unroll
      for (int ks = 0; ks < 16; ++ks) {
        ac0 = MFMA(*(const v8s*)(Wh[0] + ks * 32), Ahh[ks], ac0);
        ac1 = MFMA(*(const v8s*)(Wh[1] + ks * 32), Ahh[ks], ac1);
        ac2 = MFMA(*(const v8s*)(Wh[2] + ks * 32), Ahh[ks], ac2);
        ac3 = MFMA(*(const v8s*)(Wh[3] + ks * 32), Ahh[ks], ac3);
      }
    }

    // ---- LSTM update, fully in-register: gate rt = acc row-tile rt;
    // lane owns batch bat, hidden units j0 + q*4 + 0..3
    {
      u16 hv[4];
      #pragma unroll
      for (int r = 0; r < 4; ++r) {
        float ig = sigm(ac0[r] + bs[0][r]);
        float fg = sigm(ac1[r] + bs[1][r]);
        float gg = tanh_f(ac2[r] + bs[2][r]);
        float og = sigm(ac3[r] + bs[3][r]);
        cc[r] = fg * cc[r] + ig * gg;
        hv[r] = f2bf(og * tanh_f(cc[r]));
      }
      v2u qv;
      qv[0] = (unsigned)hv[0] | ((unsigned)hv[1] << 16);
      qv[1] = (unsigned)hv[2] | ((unsigned)hv[3] << 16);
      u16* hp = h_buf + ((t + 1) & 1) * (Bb * Hh) + bat * Hh + j0 + q * 4;
      asm volatile("global_store_dwordx2 %0, %1, off sc0 sc1"
                   :: "v"(hp), "v"(qv) : "memory");
    }

    // ---- publish: drain store, join waves, set flag (L3)
    asm volatile("s_waitcnt vmcnt(0)" ::: "memory");
    __syncthreads();
    if (tid == 0) {
      __hip_atomic_store(&flags[fbase + chunk], (unsigned)(t + 1),
                         __ATOMIC_RELAXED, __HIP_MEMORY_SCOPE_SYSTEM);
    }
  }
}

// ---------------------------------------------------------------- epilogue:
// out[b] = h_last[b,:] . lin_w + lin_b   (h_last in h_buf[0], since T even)
__global__ void k_out(const u16* __restrict__ h, const float* __restrict__ lw,
                      const float* __restrict__ lb, float* __restrict__ out)
{
  int b = blockIdx.x * 64 + threadIdx.x;
  if (b >= Bb) return;
  const u16* hr = h + b * Hh;
  float acc = 0.f;
  #pragma unroll 8
  for (int k = 0; k < Hh; ++k) acc += bf2f(hr[k]) * lw[k];
  out[b] = acc + lb[0];
}

extern "C" void kernel_launch(void* const* d_in, const int* in_sizes, int n_in,
                              void* d_out, int out_size, void* d_ws, size_t ws_size,
                              hipStream_t stream)
{
  (void)in_sizes; (void)n_in; (void)out_size; (void)ws_size;
  const float* x       = (const float*)d_in[0];
  const float* wih_mu  = (const float*)d_in[1];
  const float* wih_rho = (const float*)d_in[2];
  const float* wih_eps = (const float*)d_in[3];
  const float* whh_mu  = (const float*)d_in[4];
  const float* whh_rho = (const float*)d_in[5];
  const float* whh_eps = (const float*)d_in[6];
  const float* b_mu    = (const float*)d_in[7];
  const float* b_rho   = (const float*)d_in[8];
  const float* b_eps   = (const float*)d_in[9];
  const float* lin_w   = (const float*)d_in[10];
  const float* lin_b   = (const float*)d_in[11];
  float* out = (float*)d_out;

  // workspace layout
  u16* x_bf  = (u16*)d_ws;                       // T*B*D bf16  = 16 MB
  u16* h_buf = x_bf + (size_t)Tt * Bb * Dd;      // 2*B*H bf16  = 512 KB
  unsigned* flags = (unsigned*)(h_buf + 2 * Bb * Hh);  // 256 uints

  k_prep<<<2048, 256, 0, stream>>>(x, x_bf, flags);

  hipFuncSetAttribute(reinterpret_cast<const void*>(lstm_main),
                      hipFuncAttributeMaxDynamicSharedMemorySize, SMEM_BYTES);
  lstm_main<<<NGROUP * NCHUNK, 128, SMEM_BYTES, stream>>>(
      whh_mu, whh_rho, whh_eps, wih_mu, wih_rho, wih_eps,
      b_mu, b_rho, b_eps, x_bf, h_buf, flags);

  k_out<<<(Bb + 63) / 64, 64, 0, stream>>>(h_buf, lin_w, lin_b, out);
}